// Round 6
// baseline (26544.217 us; speedup 1.0000x reference)
//
#include <hip/hip_runtime.h>
#include <stdint.h>

// RNN_6725918786207: 2-layer tanh RNN. B=64, T=512, D_IN=64, D_MODEL=512, D_OUT=64.
// Round 8: rotation + register headroom. Round-7 post-mortem: the rotated schedule
// is CORRECT on HW (passed) but spilled (VGPR 256, 1.28GB scratch FETCH): w0[192]
// pins 192/256 arch VGPRs, margin ~0, so ANY cross-barrier live state (hp_prev,
// fpre, sunk store) spills weight regs into the dot loop (rounds 4 & 7 identical).
// Fix: move 64 w0 pair-rows into AGPRs (w0a[64]; AGPR total 256 = cap, unified
// file 512/thread) -> arch demand ~165, margin ~90. Cost: +64 accvgpr_read/step
// (~1.2% of dot). Rotation unchanged from round 7: store of data[t-1] issued AFTER
// the barrier of step t (flies under the dot), proven by the barrier of t+1, flag
// published there; flag checks are hidden preloads consumed post-dot.
// Prediction: VGPR 160-180 (go/no-go), FETCH ~58MB, k_rnn3 ~1150-1260us,
// total ~1190-1300us, VALUBusy ~55%.

typedef unsigned int u32;
typedef unsigned short u16;
typedef _Float16 f16;
typedef _Float16 h2  __attribute__((ext_vector_type(2)));
typedef _Float16 v8h __attribute__((ext_vector_type(8)));
typedef float    v4f __attribute__((ext_vector_type(4)));

#define T_STEPS 512
#define DM 512
#define BATCH 64

// ---------- small helpers ----------
__device__ __forceinline__ float f16lo(u32 u) {
    u16 s = (u16)(u & 0xffffu); f16 h; __builtin_memcpy(&h, &s, 2); return (float)h;
}
__device__ __forceinline__ float f16hi(u32 u) {
    u16 s = (u16)(u >> 16); f16 h; __builtin_memcpy(&h, &s, 2); return (float)h;
}
__device__ __forceinline__ u32 packh2(float lo, float hi) {
    f16 a = (f16)lo, b = (f16)hi; u16 ua, ub;
    __builtin_memcpy(&ua, &a, 2); __builtin_memcpy(&ub, &b, 2);
    return (u32)ua | ((u32)ub << 16);
}
__device__ __forceinline__ float fdot2u(u32 w, u32 h, float acc) {
    h2 a, b; __builtin_memcpy(&a, &w, 4); __builtin_memcpy(&b, &h, 4);
    return __builtin_amdgcn_fdot2(a, b, acc, false);
}
__device__ __forceinline__ u32 RL(u32 v, int l) {
    return (u32)__builtin_amdgcn_readlane((int)v, l);
}
__device__ __forceinline__ float tanh_fast(float z) {
    float e = __expf(2.0f * z);
    return 1.0f - 2.0f / (e + 1.0f);
}
// agent-scope (device/cross-XCD coherent, sc1) dword access
__device__ __forceinline__ u32 ld_agent(const u32* p) {
    return __hip_atomic_load(p, __ATOMIC_RELAXED, __HIP_MEMORY_SCOPE_AGENT);
}
__device__ __forceinline__ void st_agent(u32* p, u32 v) {
    __hip_atomic_store(p, v, __ATOMIC_RELAXED, __HIP_MEMORY_SCOPE_AGENT);
}

// ---------- prep kernels ----------
__global__ void k_cast_f16(const float* __restrict__ src, f16* __restrict__ dst, int n) {
    int i = blockIdx.x * blockDim.x + threadIdx.x;
    if (i < n) dst[i] = (f16)src[i];
}

// W [512][512] fp32 row-major (k-major) -> Wp [256 pair-rows][256 col-pairs] of uint2:
//   Wp[p][c].x = pack(W[2p][2c],   W[2p+1][2c])
//   Wp[p][c].y = pack(W[2p][2c+1], W[2p+1][2c+1])
__global__ void k_pack_whh(const float* __restrict__ W, uint2* __restrict__ Wp) {
    int i = blockIdx.x * blockDim.x + threadIdx.x;  // 65536
    int p = i >> 8, c = i & 255;
    int k0 = 2 * p, j0 = 2 * c;
    uint2 o;
    o.x = packh2(W[k0 * DM + j0],     W[(k0 + 1) * DM + j0]);
    o.y = packh2(W[k0 * DM + j0 + 1], W[(k0 + 1) * DM + j0 + 1]);
    Wp[p * 256 + c] = o;
}

// src fp32 [R][C] -> dst fp16 [C][R]
__global__ void k_transpose_f16(const float* __restrict__ src, f16* __restrict__ dst, int R, int C) {
    int i = blockIdx.x * blockDim.x + threadIdx.x;
    if (i < R * C) { int r = i / C, c = i % C; dst[c * R + r] = (f16)src[r * C + c]; }
}

__global__ void k_bias_sum(const float* a0, const float* b0, float* o0,
                           const float* a1, const float* b1, float* o1) {
    int i = blockIdx.x * blockDim.x + threadIdx.x;
    if (i < DM) { o0[i] = a0[i] + b0[i]; o1[i] = a1[i] + b1[i]; }
}

// zero the handshake flags with agent-scope stores
__global__ void k_zero_flags(u32* __restrict__ f, int n) {
    int i = blockIdx.x * blockDim.x + threadIdx.x;
    if (i < n) st_agent(&f[i], 0u);
}

// ---------- MFMA f16 GEMM: C[M][N] = A[M][K] @ B[K][N] + bias, B given transposed BT[N][K].
__global__ __launch_bounds__(256) void k_gemm(const f16* __restrict__ A, const f16* __restrict__ BT,
                                              void* __restrict__ Cout, const float* __restrict__ bias,
                                              int M, int N, int K, int out_f32) {
    __shared__ f16 As[64][40];
    __shared__ f16 Bs[64][40];
    int tid = threadIdx.x;
    int mb = blockIdx.x, nb = blockIdx.y;
    int l = tid & 63, w = tid >> 6;
    int q = l >> 4, mr = l & 15;

    int sr = tid >> 2;
    int ko = (tid & 3) * 8;
    const f16* gA = A + (size_t)(mb * 64 + sr) * K + ko;
    const f16* gB = BT + (size_t)(nb * 64 + sr) * K + ko;

    v4f acc[4];
    #pragma unroll
    for (int nt = 0; nt < 4; ++nt) acc[nt] = (v4f){0.f, 0.f, 0.f, 0.f};

    for (int kt = 0; kt < K; kt += 32) {
        *(uint4*)&As[sr][ko] = *(const uint4*)(gA + kt);
        *(uint4*)&Bs[sr][ko] = *(const uint4*)(gB + kt);
        __syncthreads();
        v8h a = *(const v8h*)&As[w * 16 + mr][q * 8];
        #pragma unroll
        for (int nt = 0; nt < 4; ++nt) {
            v8h b = *(const v8h*)&Bs[nt * 16 + mr][q * 8];
            acc[nt] = __builtin_amdgcn_mfma_f32_16x16x32_f16(a, b, acc[nt], 0, 0, 0);
        }
        __syncthreads();
    }

    int row0 = mb * 64 + w * 16 + q * 4;
    #pragma unroll
    for (int nt = 0; nt < 4; ++nt) {
        int col = nb * 64 + nt * 16 + mr;
        float bv = bias[col];
        #pragma unroll
        for (int r = 0; r < 4; ++r) {
            float v = acc[nt][r] + bv;
            if (out_f32) ((float*)Cout)[(size_t)(row0 + r) * N + col] = v;
            else         ((f16*)Cout)[(size_t)(row0 + r) * N + col] = (f16)v;
        }
    }
}

// ---------- fused 3-stage pipelined recurrence ----------
// grid (64, 3): blockIdx.x = batch, blockIdx.y = role.
//   role 0 (A): h0[t] = tanh(X0[t] + h0[t-1] @ Whh0)  -> H0 (sc1)
//   role 1 (B): x1[t] = h0[t] @ Wih1 + bias1          -> X1 (sc1)
//   role 2 (C): h1[t] = tanh(x1[t] + h1[t-1] @ Whh1)  -> H1 (plain)
// Weights per thread (cols 2c, 2c+1): pair-rows 0..127 lo-col in ArchVGPR w0[128],
// pair-rows 128..191 lo-col in AGPR w0a[64], all hi-col in AGPR w1a[192]
// (AGPR total 256 = cap; arch demand ~165 -> ~90 regs margin for rotation state).
// Rotated schedule per role, one barrier per step at the top:
//   barrier (proves store issued at top of t-1, i.e. data[t-2])
//   -> tid0 publishes flag[t-2]
//   -> issue store of data[t-1] (held in a register across the barrier)
//   -> issue this step's loads + a hidden flag-load for the step after next
//   -> dot -> result into register; spin only if the hidden flag-load saw 0.
// No step waits for a store ack or a flag round trip. All 192 WGs co-resident
// (1 WG/CU by LDS) -> spins deadlock-free; bounded-spin guard fails fast.

#define COMPUTE_DOT() do {                                                        \
    _Pragma("unroll")                                                             \
    for (int p = 0; p < 128; p += 2) {                                            \
        u32 hA = RL(hr[p >> 6], p & 63);                                          \
        u32 hB = RL(hr[(p + 1) >> 6], (p + 1) & 63);                              \
        u32 y0, y1;                                                               \
        asm volatile("v_accvgpr_read_b32 %0, %1" : "=v"(y0) : "a"(w1a[p]));       \
        asm volatile("v_accvgpr_read_b32 %0, %1" : "=v"(y1) : "a"(w1a[p + 1]));   \
        a0 = fdot2u(w0[p], hA, a0);                                               \
        a1 = fdot2u(y0, hA, a1);                                                  \
        a2 = fdot2u(w0[p + 1], hB, a2);                                           \
        a3 = fdot2u(y1, hB, a3);                                                  \
    }                                                                             \
    _Pragma("unroll")                                                             \
    for (int p = 128; p < 192; p += 2) {                                          \
        u32 hA = RL(hr[2], p & 63);                                               \
        u32 hB = RL(hr[2], (p + 1) & 63);                                         \
        u32 x0, x1, y0, y1;                                                       \
        asm volatile("v_accvgpr_read_b32 %0, %1" : "=v"(x0) : "a"(w0a[p - 128])); \
        asm volatile("v_accvgpr_read_b32 %0, %1" : "=v"(x1) : "a"(w0a[p - 127])); \
        asm volatile("v_accvgpr_read_b32 %0, %1" : "=v"(y0) : "a"(w1a[p]));       \
        asm volatile("v_accvgpr_read_b32 %0, %1" : "=v"(y1) : "a"(w1a[p + 1]));   \
        a0 = fdot2u(x0, hA, a0);                                                  \
        a1 = fdot2u(y0, hA, a1);                                                  \
        a2 = fdot2u(x1, hB, a2);                                                  \
        a3 = fdot2u(y1, hB, a3);                                                  \
    }                                                                             \
    _Pragma("unroll")                                                             \
    for (int q2 = 0; q2 < 32; ++q2) {                                             \
        uint4 wv = ldsW[q2 * 256 + tid];                                          \
        int p0 = 192 + 2 * q2;                                                    \
        u32 hA = RL(hr[3], p0 & 63);                                              \
        u32 hB = RL(hr[3], (p0 + 1) & 63);                                        \
        a0 = fdot2u(wv.x, hA, a0);                                                \
        a1 = fdot2u(wv.y, hA, a1);                                                \
        a2 = fdot2u(wv.z, hB, a2);                                                \
        a3 = fdot2u(wv.w, hB, a3);                                                \
    }                                                                             \
} while (0)

// tid0-only spin. Bounded: guard turns a coherence surprise into a fast wrong
// answer instead of a harness hang.
#define SPIN(ptr) do { int g_ = 0;                                                \
    while (!dead && __hip_atomic_load((ptr), __ATOMIC_RELAXED,                    \
                                      __HIP_MEMORY_SCOPE_AGENT) == 0u) {          \
        __builtin_amdgcn_s_sleep(2);                                              \
        if (++g_ > (1 << 21)) dead = 1;                                           \
    } } while (0)

__global__ __launch_bounds__(256, 1) void k_rnn3(const u32* __restrict__ X0,
                                                 u32* __restrict__ H0,
                                                 u32* __restrict__ X1,
                                                 u32* __restrict__ H1,
                                                 const uint2* __restrict__ Wp0,
                                                 const uint2* __restrict__ WpI,
                                                 const uint2* __restrict__ Wp1,
                                                 const float* __restrict__ bias1,
                                                 u32* __restrict__ flagA,
                                                 u32* __restrict__ flagB) {
    __shared__ uint4 ldsW[32 * 256];   // 128 KiB: pair-rows 192..255
    __shared__ u32 hbuf[2][256];       // double-buffered recurrent h (roles A, C)

    int b = blockIdx.x, role = blockIdx.y;
    int tid = threadIdx.x, lane = tid & 63;

    const uint2* Wp = (role == 0) ? Wp0 : (role == 1) ? WpI : Wp1;

    // stage LDS-resident part of W
    for (int i = tid; i < 32 * 256; i += 256) {
        int q2 = i >> 8, c = i & 255;
        uint2 lo = Wp[(192 + 2 * q2) * 256 + c];
        uint2 hi = Wp[(193 + 2 * q2) * 256 + c];
        ldsW[i] = make_uint4(lo.x, lo.y, hi.x, hi.y);
    }

    // register-resident W: 128 ArchVGPR (w0) + 64 AGPR (w0a) + 192 AGPR (w1a)
    u32 w0[128];
    u32 w0a[64];
    u32 w1a[192];
    #pragma unroll
    for (int p = 0; p < 192; ++p) {
        uint2 t2 = Wp[p * 256 + tid];
        if (p < 128) {
            asm volatile("v_mov_b32 %0, %1" : "=v"(w0[p]) : "v"(t2.x));
        } else {
            asm volatile("v_accvgpr_write_b32 %0, %1" : "=a"(w0a[p - 128]) : "v"(t2.x));
        }
        asm volatile("v_accvgpr_write_b32 %0, %1" : "=a"(w1a[p]) : "v"(t2.y));
    }

    hbuf[0][tid] = 0u;
    __syncthreads();

    if (role == 0) {
        // ---- A: layer-0 recurrence; h[t] stored during step t+1 ----
        const u32* Xb = X0 + (size_t)b * T_STEPS * 256;
        u32* Hb = H0 + (size_t)b * T_STEPS * 256;
        u32* fA = flagA + b * T_STEPS;
        int cur = 0;
        u32 hp_prev = 0u;
        for (int t = 0; t < T_STEPS; ++t) {
            __syncthreads();                        // proves Hb[t-2] (issued top of t-1)
            if (tid == 0 && t >= 2) st_agent(&fA[t - 2], 1u);
            if (t >= 1) st_agent(&Hb[(size_t)(t - 1) * 256 + tid], hp_prev); // flies under dot
            u32 hr[4];
            #pragma unroll
            for (int r = 0; r < 4; ++r) hr[r] = hbuf[cur][r * 64 + lane];
            u32 xv = Xb[t * 256 + tid];             // consumed at the end

            float a0 = 0.f, a1 = 0.f, a2 = 0.f, a3 = 0.f;
            COMPUTE_DOT();

            float z0 = a0 + f16lo(xv) + a2;
            float z1 = a1 + f16hi(xv) + a3;
            u32 hp = packh2(tanh_fast(z0), tanh_fast(z1));
            hbuf[cur ^ 1][tid] = hp;
            hp_prev = hp;
            cur ^= 1;
        }
        __syncthreads();                            // proves Hb[T-2]
        if (tid == 0) st_agent(&fA[T_STEPS - 2], 1u);
        st_agent(&Hb[(size_t)(T_STEPS - 1) * 256 + tid], hp_prev);
        __syncthreads();                            // drains Hb[T-1]
        if (tid == 0) st_agent(&fA[T_STEPS - 1], 1u);
    } else if (role == 1) {
        // ---- B: x1[t] = h0[t] @ Wih1 + bias1; h0[t+1] prefetched over the dot ----
        const u32* Hb = H0 + (size_t)b * T_STEPS * 256;
        u32* Xb1 = X1 + (size_t)b * T_STEPS * 256;
        u32* fA = flagA + b * T_STEPS;
        u32* fB = flagB + b * T_STEPS;
        float bl = bias1[2 * tid], bh = bias1[2 * tid + 1];
        int dead = 0;
        u32 xp_prev = 0u;

        if (tid == 0) { SPIN(&fA[0]); SPIN(&fA[1]); }   // bootstrap: h0[0], h0[1] ready
        __syncthreads();
        u32 hr[4];
        #pragma unroll
        for (int r = 0; r < 4; ++r) hr[r] = ld_agent(&Hb[r * 64 + lane]);

        for (int t = 0; t < T_STEPS; ++t) {
            __syncthreads();                        // proves Xb1[t-2] (issued top of t-1)
            if (tid == 0 && t >= 2) st_agent(&fB[t - 2], 1u);
            if (t >= 1) st_agent(&Xb1[(size_t)(t - 1) * 256 + tid], xp_prev);
            u32 hn[4] = {0u, 0u, 0u, 0u};
            if (t + 1 < T_STEPS) {                  // fA[t+1] confirmed last step
                #pragma unroll
                for (int r = 0; r < 4; ++r)
                    hn[r] = ld_agent(&Hb[(size_t)(t + 1) * 256 + r * 64 + lane]);
            }
            u32 fpre = 1u;                          // hidden flag-load, consumed post-dot
            if (tid == 0 && t + 2 < T_STEPS) fpre = ld_agent(&fA[t + 2]);

            float a0 = 0.f, a1 = 0.f, a2 = 0.f, a3 = 0.f;
            COMPUTE_DOT();

            xp_prev = packh2(a0 + a2 + bl, a1 + a3 + bh);
            if (tid == 0 && t + 2 < T_STEPS && fpre == 0u) SPIN(&fA[t + 2]);
            #pragma unroll
            for (int r = 0; r < 4; ++r) hr[r] = hn[r];
        }
        __syncthreads();                            // proves Xb1[T-2]
        if (tid == 0) st_agent(&fB[T_STEPS - 2], 1u);
        st_agent(&Xb1[(size_t)(T_STEPS - 1) * 256 + tid], xp_prev);
        __syncthreads();                            // drains Xb1[T-1]
        if (tid == 0) st_agent(&fB[T_STEPS - 1], 1u);
    } else {
        // ---- C: layer-1 recurrence; x1[t] load and fB[t+1] check hidden under dot ----
        const u32* Xb1 = X1 + (size_t)b * T_STEPS * 256;
        u32* Hb1 = H1 + (size_t)b * T_STEPS * 256;
        u32* fB = flagB + b * T_STEPS;
        int dead = 0;
        int cur = 0;
        u32 hp_prev = 0u;
        if (tid == 0) SPIN(&fB[0]);                 // bootstrap: x1[0] ready
        for (int t = 0; t < T_STEPS; ++t) {
            __syncthreads();                        // releases bootstrap/hidden-spin gate
            if (t >= 1) Hb1[(size_t)(t - 1) * 256 + tid] = hp_prev;  // plain, flies under dot
            u32 xv = ld_agent(&Xb1[t * 256 + tid]); // consumed after the dot
            u32 fpre = 1u;
            if (tid == 0 && t + 1 < T_STEPS) fpre = ld_agent(&fB[t + 1]);

            u32 hr[4];
            #pragma unroll
            for (int r = 0; r < 4; ++r) hr[r] = hbuf[cur][r * 64 + lane];

            float a0 = 0.f, a1 = 0.f, a2 = 0.f, a3 = 0.f;
            COMPUTE_DOT();

            float z0 = a0 + f16lo(xv) + a2;
            float z1 = a1 + f16hi(xv) + a3;
            u32 hp = packh2(tanh_fast(z0), tanh_fast(z1));
            hbuf[cur ^ 1][tid] = hp;
            hp_prev = hp;
            if (tid == 0 && t + 1 < T_STEPS && fpre == 0u) SPIN(&fB[t + 1]);
            cur ^= 1;
        }
        Hb1[(size_t)(T_STEPS - 1) * 256 + tid] = hp_prev;  // drained at kernel end
    }
}

// ---------- launch ----------
extern "C" void kernel_launch(void* const* d_in, const int* in_sizes, int n_in,
                              void* d_out, int out_size, void* d_ws, size_t ws_size,
                              hipStream_t stream) {
    (void)in_sizes; (void)n_in; (void)out_size; (void)ws_size;
    const float* data = (const float*)d_in[0];
    const float* Wih0 = (const float*)d_in[1];
    const float* bih0 = (const float*)d_in[2];
    const float* Whh0 = (const float*)d_in[3];
    const float* bhh0 = (const float*)d_in[4];
    const float* Wih1 = (const float*)d_in[5];
    const float* bih1 = (const float*)d_in[6];
    const float* Whh1 = (const float*)d_in[7];
    const float* bhh1 = (const float*)d_in[8];
    const float* Wout = (const float*)d_in[9];
    const float* bout = (const float*)d_in[10];

    char* ws = (char*)d_ws;
    // workspace layout (bytes); total = 106,565,632
    f16*   X0    = (f16*)(ws + 0);           // [32768][512] f16; H1 aliased here:
                                             // C stores H1[b][t] during C-step t+1;
                                             // C lags A by ~5 slots, so A read
                                             // X0[b][t] long before.
    f16*   H0    = (f16*)(ws + 33554432);    // [32768][512] f16 (A -> B, sc1)
    f16*   X1    = (f16*)(ws + 67108864);    // [32768][512] f16 (B -> C, sc1)
    f16*   D16   = (f16*)(ws + 100663296);   // data fp16 [32768][64] (dead after X0 GEMM)
    u32*   flagA = (u32*)(ws + 100663296);   // 128 KiB, aliases D16 head (zeroed post-GEMM)
    u32*   flagB = (u32*)(ws + 100794368);   // 128 KiB
    uint2* Wp0   = (uint2*)(ws + 104857600); // packed Whh0
    uint2* WpI   = (uint2*)(ws + 105381888); // packed Wih1
    uint2* Wp1   = (uint2*)(ws + 105906176); // packed Whh1
    f16*   WT0   = (f16*)(ws + 106430464);   // Wih0^T [512][64]
    f16*   WoT   = (f16*)(ws + 106496000);   // Wout^T [64][512]
    float* bias0 = (float*)(ws + 106561536);
    float* bias1 = (float*)(ws + 106563584);

    // prep
    k_cast_f16<<<8192, 256, 0, stream>>>(data, D16, 64 * 512 * 64);
    k_pack_whh<<<256, 256, 0, stream>>>(Whh0, Wp0);
    k_pack_whh<<<256, 256, 0, stream>>>(Wih1, WpI);
    k_pack_whh<<<256, 256, 0, stream>>>(Whh1, Wp1);
    k_transpose_f16<<<128, 256, 0, stream>>>(Wih0, WT0, 64, 512);
    k_transpose_f16<<<128, 256, 0, stream>>>(Wout, WoT, 512, 64);
    k_bias_sum<<<2, 256, 0, stream>>>(bih0, bhh0, bias0, bih1, bhh1, bias1);

    // X0 = data @ Wih0 + bias0  (reads D16, must precede flag zeroing)
    dim3 gX(512, 8);
    k_gemm<<<gX, 256, 0, stream>>>(D16, WT0, (void*)X0, bias0, 32768, 512, 64, 0);

    // zero flags (flagA..flagB contiguous = 65536 words) with sc1 stores
    k_zero_flags<<<256, 256, 0, stream>>>(flagA, 2 * BATCH * T_STEPS);

    // fused 3-stage pipelined recurrence: 192 WGs, all co-resident
    k_rnn3<<<dim3(64, 3), 256, 0, stream>>>((const u32*)X0, (u32*)H0, (u32*)X1,
                                            (u32*)X0 /* H1 alias */,
                                            Wp0, WpI, Wp1, bias1, flagA, flagB);

    // OUT = H1 @ Wout + bout -> fp32 d_out
    dim3 gO(512, 1);
    k_gemm<<<gO, 256, 0, stream>>>((const f16*)X0 /* H1 */, WoT, d_out, bout, 32768, 64, 512, 1);
}

// Round 7
// 1564.799 us; speedup vs baseline: 16.9633x; 16.9633x over previous
//
#include <hip/hip_runtime.h>
#include <stdint.h>

// RNN_6725918786207: 2-layer tanh RNN. B=64, T=512, D_IN=64, D_MODEL=512, D_OUT=64.
// Round 9: remove the vmcnt(0) drain from the per-step barrier with ZERO new live
// state. r4/r7/r8 post-mortem law: any register held across the barrier spills the
// weight arrays (216->256 VGPR, GBs of scratch). r3/r5 (stable, 1515us) differ from
// the rotations only in having no cross-barrier state. The 0.76us/step overhead is
// __syncthreads' compiler-emitted "s_waitcnt vmcnt(0)" draining the just-issued sc1
// store. Fix: in-loop barrier = asm "s_waitcnt lgkmcnt(0); s_barrier" (LDS-only
// wait, memory clobber). Store-completion proof for flags comes free from the
// natural x-load consumption (issue order store(t-1) -> load x(t) -> use x(t);
// vmcnt retires in order, and the use-wait fires ~2us after the store was issued).
// Barrier at top of step s thus proves store(s-2) for all threads -> publish
// flag[s-2] after it (lag 2, ~5us deeper fill). Role B's hn->hr copy is register-
// renamed (no forced wait), so B gets one operand-free "s_waitcnt vmcnt(1)" at
// step end (leaves only its own store outstanding; proves hn + store(t-1)).
// Code shape otherwise IDENTICAL to round 5 (216 VGPR).
// Prediction: VGPR ~216 (go/no-go), FETCH ~58MB, k_rnn3 ~1180-1260us,
// total ~1215-1300us, VALUBusy ~55%.

typedef unsigned int u32;
typedef unsigned short u16;
typedef _Float16 f16;
typedef _Float16 h2  __attribute__((ext_vector_type(2)));
typedef _Float16 v8h __attribute__((ext_vector_type(8)));
typedef float    v4f __attribute__((ext_vector_type(4)));

#define T_STEPS 512
#define DM 512
#define BATCH 64

// ---------- small helpers ----------
__device__ __forceinline__ float f16lo(u32 u) {
    u16 s = (u16)(u & 0xffffu); f16 h; __builtin_memcpy(&h, &s, 2); return (float)h;
}
__device__ __forceinline__ float f16hi(u32 u) {
    u16 s = (u16)(u >> 16); f16 h; __builtin_memcpy(&h, &s, 2); return (float)h;
}
__device__ __forceinline__ u32 packh2(float lo, float hi) {
    f16 a = (f16)lo, b = (f16)hi; u16 ua, ub;
    __builtin_memcpy(&ua, &a, 2); __builtin_memcpy(&ub, &b, 2);
    return (u32)ua | ((u32)ub << 16);
}
__device__ __forceinline__ float fdot2u(u32 w, u32 h, float acc) {
    h2 a, b; __builtin_memcpy(&a, &w, 4); __builtin_memcpy(&b, &h, 4);
    return __builtin_amdgcn_fdot2(a, b, acc, false);
}
__device__ __forceinline__ u32 RL(u32 v, int l) {
    return (u32)__builtin_amdgcn_readlane((int)v, l);
}
__device__ __forceinline__ float tanh_fast(float z) {
    float e = __expf(2.0f * z);
    return 1.0f - 2.0f / (e + 1.0f);
}
// agent-scope (device/cross-XCD coherent, sc1) dword access
__device__ __forceinline__ u32 ld_agent(const u32* p) {
    return __hip_atomic_load(p, __ATOMIC_RELAXED, __HIP_MEMORY_SCOPE_AGENT);
}
__device__ __forceinline__ void st_agent(u32* p, u32 v) {
    __hip_atomic_store(p, v, __ATOMIC_RELAXED, __HIP_MEMORY_SCOPE_AGENT);
}

// LDS-only barrier: waits DS ops (hbuf double-buffer ordering) but does NOT drain
// vmcnt -> the per-step sc1 data store keeps flying under the next dot. "memory"
// clobber pins all memory ops on their side of the barrier.
#define BARRIER_LG() asm volatile("s_waitcnt lgkmcnt(0)\n\ts_barrier" ::: "memory")

// ---------- prep kernels ----------
__global__ void k_cast_f16(const float* __restrict__ src, f16* __restrict__ dst, int n) {
    int i = blockIdx.x * blockDim.x + threadIdx.x;
    if (i < n) dst[i] = (f16)src[i];
}

// W [512][512] fp32 row-major (k-major) -> Wp [256 pair-rows][256 col-pairs] of uint2:
//   Wp[p][c].x = pack(W[2p][2c],   W[2p+1][2c])
//   Wp[p][c].y = pack(W[2p][2c+1], W[2p+1][2c+1])
__global__ void k_pack_whh(const float* __restrict__ W, uint2* __restrict__ Wp) {
    int i = blockIdx.x * blockDim.x + threadIdx.x;  // 65536
    int p = i >> 8, c = i & 255;
    int k0 = 2 * p, j0 = 2 * c;
    uint2 o;
    o.x = packh2(W[k0 * DM + j0],     W[(k0 + 1) * DM + j0]);
    o.y = packh2(W[k0 * DM + j0 + 1], W[(k0 + 1) * DM + j0 + 1]);
    Wp[p * 256 + c] = o;
}

// src fp32 [R][C] -> dst fp16 [C][R]
__global__ void k_transpose_f16(const float* __restrict__ src, f16* __restrict__ dst, int R, int C) {
    int i = blockIdx.x * blockDim.x + threadIdx.x;
    if (i < R * C) { int r = i / C, c = i % C; dst[c * R + r] = (f16)src[r * C + c]; }
}

__global__ void k_bias_sum(const float* a0, const float* b0, float* o0,
                           const float* a1, const float* b1, float* o1) {
    int i = blockIdx.x * blockDim.x + threadIdx.x;
    if (i < DM) { o0[i] = a0[i] + b0[i]; o1[i] = a1[i] + b1[i]; }
}

// zero the handshake flags with agent-scope stores
__global__ void k_zero_flags(u32* __restrict__ f, int n) {
    int i = blockIdx.x * blockDim.x + threadIdx.x;
    if (i < n) st_agent(&f[i], 0u);
}

// ---------- MFMA f16 GEMM: C[M][N] = A[M][K] @ B[K][N] + bias, B given transposed BT[N][K].
__global__ __launch_bounds__(256) void k_gemm(const f16* __restrict__ A, const f16* __restrict__ BT,
                                              void* __restrict__ Cout, const float* __restrict__ bias,
                                              int M, int N, int K, int out_f32) {
    __shared__ f16 As[64][40];
    __shared__ f16 Bs[64][40];
    int tid = threadIdx.x;
    int mb = blockIdx.x, nb = blockIdx.y;
    int l = tid & 63, w = tid >> 6;
    int q = l >> 4, mr = l & 15;

    int sr = tid >> 2;
    int ko = (tid & 3) * 8;
    const f16* gA = A + (size_t)(mb * 64 + sr) * K + ko;
    const f16* gB = BT + (size_t)(nb * 64 + sr) * K + ko;

    v4f acc[4];
    #pragma unroll
    for (int nt = 0; nt < 4; ++nt) acc[nt] = (v4f){0.f, 0.f, 0.f, 0.f};

    for (int kt = 0; kt < K; kt += 32) {
        *(uint4*)&As[sr][ko] = *(const uint4*)(gA + kt);
        *(uint4*)&Bs[sr][ko] = *(const uint4*)(gB + kt);
        __syncthreads();
        v8h a = *(const v8h*)&As[w * 16 + mr][q * 8];
        #pragma unroll
        for (int nt = 0; nt < 4; ++nt) {
            v8h b = *(const v8h*)&Bs[nt * 16 + mr][q * 8];
            acc[nt] = __builtin_amdgcn_mfma_f32_16x16x32_f16(a, b, acc[nt], 0, 0, 0);
        }
        __syncthreads();
    }

    int row0 = mb * 64 + w * 16 + q * 4;
    #pragma unroll
    for (int nt = 0; nt < 4; ++nt) {
        int col = nb * 64 + nt * 16 + mr;
        float bv = bias[col];
        #pragma unroll
        for (int r = 0; r < 4; ++r) {
            float v = acc[nt][r] + bv;
            if (out_f32) ((float*)Cout)[(size_t)(row0 + r) * N + col] = v;
            else         ((f16*)Cout)[(size_t)(row0 + r) * N + col] = (f16)v;
        }
    }
}

// ---------- fused 3-stage pipelined recurrence ----------
// grid (64, 3): blockIdx.x = batch, blockIdx.y = role.
//   role 0 (A): h0[t] = tanh(X0[t] + h0[t-1] @ Whh0)  -> H0 (sc1)
//   role 1 (B): x1[t] = h0[t] @ Wih1 + bias1          -> X1 (sc1)
//   role 2 (C): h1[t] = tanh(x1[t] + h1[t-1] @ Whh1)  -> H1 (plain)
// Per step: BARRIER_LG (LDS wait only, no vmem drain) -> tid0 publishes flag[t-2]
// (proven: every thread's step-(t-1) x-load consumption waited out store(t-2);
// vmcnt retires in issue order) -> loads -> dot -> store issued at end, flying
// under the next step's dot. Round-3 code shape: no state lives across a barrier.
// All 192 WGs co-resident (1 WG/CU by LDS) -> spins deadlock-free; bounded-spin
// guard turns any surprise into a fast wrong answer instead of a hang.

#define COMPUTE_DOT() do {                                                        \
    _Pragma("unroll")                                                             \
    for (int p = 0; p < 192; p += 2) {                                            \
        u32 hA = RL(hr[p >> 6], p & 63);                                          \
        u32 hB = RL(hr[(p + 1) >> 6], (p + 1) & 63);                              \
        u32 y0, y1;                                                               \
        asm volatile("v_accvgpr_read_b32 %0, %1" : "=v"(y0) : "a"(w1a[p]));       \
        asm volatile("v_accvgpr_read_b32 %0, %1" : "=v"(y1) : "a"(w1a[p + 1]));   \
        a0 = fdot2u(w0[p], hA, a0);                                               \
        a1 = fdot2u(y0, hA, a1);                                                  \
        a2 = fdot2u(w0[p + 1], hB, a2);                                           \
        a3 = fdot2u(y1, hB, a3);                                                  \
    }                                                                             \
    _Pragma("unroll")                                                             \
    for (int q2 = 0; q2 < 32; ++q2) {                                             \
        uint4 wv = ldsW[q2 * 256 + tid];                                          \
        int p0 = 192 + 2 * q2;                                                    \
        u32 hA = RL(hr[3], p0 & 63);                                              \
        u32 hB = RL(hr[3], (p0 + 1) & 63);                                        \
        a0 = fdot2u(wv.x, hA, a0);                                                \
        a1 = fdot2u(wv.y, hA, a1);                                                \
        a2 = fdot2u(wv.z, hB, a2);                                                \
        a3 = fdot2u(wv.w, hB, a3);                                                \
    }                                                                             \
} while (0)

// tid0-only spin. Bounded: guard turns a coherence surprise into a fast wrong
// answer instead of a harness hang.
#define SPIN(ptr) do { int g_ = 0;                                                \
    while (!dead && __hip_atomic_load((ptr), __ATOMIC_RELAXED,                    \
                                      __HIP_MEMORY_SCOPE_AGENT) == 0u) {          \
        __builtin_amdgcn_s_sleep(2);                                              \
        if (++g_ > (1 << 21)) dead = 1;                                           \
    } } while (0)

__global__ __launch_bounds__(256, 1) void k_rnn3(const u32* __restrict__ X0,
                                                 u32* __restrict__ H0,
                                                 u32* __restrict__ X1,
                                                 u32* __restrict__ H1,
                                                 const uint2* __restrict__ Wp0,
                                                 const uint2* __restrict__ WpI,
                                                 const uint2* __restrict__ Wp1,
                                                 const float* __restrict__ bias1,
                                                 u32* __restrict__ flagA,
                                                 u32* __restrict__ flagB) {
    __shared__ uint4 ldsW[32 * 256];   // 128 KiB: pair-rows 192..255
    __shared__ u32 hbuf[2][256];       // double-buffered recurrent h (roles A, C)

    int b = blockIdx.x, role = blockIdx.y;
    int tid = threadIdx.x, lane = tid & 63;

    const uint2* Wp = (role == 0) ? Wp0 : (role == 1) ? WpI : Wp1;

    // stage LDS-resident part of W
    for (int i = tid; i < 32 * 256; i += 256) {
        int q2 = i >> 8, c = i & 255;
        uint2 lo = Wp[(192 + 2 * q2) * 256 + c];
        uint2 hi = Wp[(193 + 2 * q2) * 256 + c];
        ldsW[i] = make_uint4(lo.x, lo.y, hi.x, hi.y);
    }

    // register-resident part: 192 ArchVGPRs (w0) + 192 AGPRs (w1a)
    u32 w0[192];
    u32 w1a[192];
    #pragma unroll
    for (int p = 0; p < 192; ++p) {
        uint2 t2 = Wp[p * 256 + tid];
        asm volatile("v_mov_b32 %0, %1" : "=v"(w0[p]) : "v"(t2.x));
        asm volatile("v_accvgpr_write_b32 %0, %1" : "=a"(w1a[p]) : "v"(t2.y));
    }

    hbuf[0][tid] = 0u;
    __syncthreads();

    if (role == 0) {
        // ---- A: layer-0 recurrence; store flies under step t+1's dot ----
        const u32* Xb = X0 + (size_t)b * T_STEPS * 256;
        u32* Hb = H0 + (size_t)b * T_STEPS * 256;
        u32* fA = flagA + b * T_STEPS;
        int cur = 0;
        for (int t = 0; t < T_STEPS; ++t) {
            BARRIER_LG();                           // LDS wait only; no vmem drain
            if (tid == 0 && t >= 2) st_agent(&fA[t - 2], 1u);  // proven by xv(t-1) use
            u32 hr[4];
            #pragma unroll
            for (int r = 0; r < 4; ++r) hr[r] = hbuf[cur][r * 64 + lane];
            u32 xv = Xb[t * 256 + tid];             // consumed at end: proves store(t-1)

            float a0 = 0.f, a1 = 0.f, a2 = 0.f, a3 = 0.f;
            COMPUTE_DOT();

            float z0 = a0 + f16lo(xv) + a2;
            float z1 = a1 + f16hi(xv) + a3;
            u32 hp = packh2(tanh_fast(z0), tanh_fast(z1));
            hbuf[cur ^ 1][tid] = hp;
            st_agent(&Hb[t * 256 + tid], hp);       // fire-and-forget
            cur ^= 1;
        }
        __syncthreads();                            // full drain: stores T-2, T-1 proven
        if (tid == 0) { st_agent(&fA[T_STEPS - 2], 1u); st_agent(&fA[T_STEPS - 1], 1u); }
    } else if (role == 1) {
        // ---- B: x1[t] = h0[t] @ Wih1 + bias1; h0[t+1] prefetched over the dot ----
        const u32* Hb = H0 + (size_t)b * T_STEPS * 256;
        u32* Xb1 = X1 + (size_t)b * T_STEPS * 256;
        u32* fA = flagA + b * T_STEPS;
        u32* fB = flagB + b * T_STEPS;
        float bl = bias1[2 * tid], bh = bias1[2 * tid + 1];
        int dead = 0;

        if (tid == 0) SPIN(&fA[0]);
        BARRIER_LG();
        u32 hr[4];
        #pragma unroll
        for (int r = 0; r < 4; ++r) hr[r] = ld_agent(&Hb[r * 64 + lane]);

        for (int t = 0; t < T_STEPS; ++t) {
            if (tid == 0 && t + 1 < T_STEPS) SPIN(&fA[t + 1]);  // set slots ago: immediate
            BARRIER_LG();
            if (tid == 0 && t >= 2) st_agent(&fB[t - 2], 1u);   // proven by tail vmcnt(1)
            u32 hn[4] = {0u, 0u, 0u, 0u};
            if (t + 1 < T_STEPS) {
                #pragma unroll
                for (int r = 0; r < 4; ++r)
                    hn[r] = ld_agent(&Hb[(size_t)(t + 1) * 256 + r * 64 + lane]);
            }

            float a0 = 0.f, a1 = 0.f, a2 = 0.f, a3 = 0.f;
            COMPUTE_DOT();

            u32 xp = packh2(a0 + a2 + bl, a1 + a3 + bh);
            st_agent(&Xb1[t * 256 + tid], xp);      // fire-and-forget
            // leave only the just-issued store outstanding: forces hn(t) returned
            // and (by in-order retire) store(t-1) complete — ~0 cost, both are old
            asm volatile("s_waitcnt vmcnt(1)" ::: "memory");
            #pragma unroll
            for (int r = 0; r < 4; ++r) hr[r] = hn[r];
        }
        __syncthreads();                            // full drain: stores T-2, T-1 proven
        if (tid == 0) { st_agent(&fB[T_STEPS - 2], 1u); st_agent(&fB[T_STEPS - 1], 1u); }
    } else {
        // ---- C: layer-1 recurrence; x1[t] load hidden under the dot ----
        const u32* Xb1 = X1 + (size_t)b * T_STEPS * 256;
        u32* Hb1 = H1 + (size_t)b * T_STEPS * 256;
        u32* fB = flagB + b * T_STEPS;
        int dead = 0;
        int cur = 0;
        for (int t = 0; t < T_STEPS; ++t) {
            if (tid == 0) SPIN(&fB[t]);             // immediate in steady state
            BARRIER_LG();
            u32 xv = ld_agent(&Xb1[t * 256 + tid]); // consumed after the dot

            u32 hr[4];
            #pragma unroll
            for (int r = 0; r < 4; ++r) hr[r] = hbuf[cur][r * 64 + lane];

            float a0 = 0.f, a1 = 0.f, a2 = 0.f, a3 = 0.f;
            COMPUTE_DOT();

            float z0 = a0 + f16lo(xv) + a2;
            float z1 = a1 + f16hi(xv) + a3;
            u32 hp = packh2(tanh_fast(z0), tanh_fast(z1));
            hbuf[cur ^ 1][tid] = hp;
            Hb1[t * 256 + tid] = hp;                // plain fire-and-forget
            cur ^= 1;
        }
        // final H1 store drained by kernel-end implicit release
    }
}

// ---------- launch ----------
extern "C" void kernel_launch(void* const* d_in, const int* in_sizes, int n_in,
                              void* d_out, int out_size, void* d_ws, size_t ws_size,
                              hipStream_t stream) {
    (void)in_sizes; (void)n_in; (void)out_size; (void)ws_size;
    const float* data = (const float*)d_in[0];
    const float* Wih0 = (const float*)d_in[1];
    const float* bih0 = (const float*)d_in[2];
    const float* Whh0 = (const float*)d_in[3];
    const float* bhh0 = (const float*)d_in[4];
    const float* Wih1 = (const float*)d_in[5];
    const float* bih1 = (const float*)d_in[6];
    const float* Whh1 = (const float*)d_in[7];
    const float* bhh1 = (const float*)d_in[8];
    const float* Wout = (const float*)d_in[9];
    const float* bout = (const float*)d_in[10];

    char* ws = (char*)d_ws;
    // workspace layout (bytes); total = 106,565,632
    f16*   X0    = (f16*)(ws + 0);           // [32768][512] f16; H1 aliased here:
                                             // C writes H1[b][t] only after fB[t] <-
                                             // A far past step t, so A read X0[b][t]
                                             // long before.
    f16*   H0    = (f16*)(ws + 33554432);    // [32768][512] f16 (A -> B, sc1)
    f16*   X1    = (f16*)(ws + 67108864);    // [32768][512] f16 (B -> C, sc1)
    f16*   D16   = (f16*)(ws + 100663296);   // data fp16 [32768][64] (dead after X0 GEMM)
    u32*   flagA = (u32*)(ws + 100663296);   // 128 KiB, aliases D16 head (zeroed post-GEMM)
    u32*   flagB = (u32*)(ws + 100794368);   // 128 KiB
    uint2* Wp0   = (uint2*)(ws + 104857600); // packed Whh0
    uint2* WpI   = (uint2*)(ws + 105381888); // packed Wih1
    uint2* Wp1   = (uint2*)(ws + 105906176); // packed Whh1
    f16*   WT0   = (f16*)(ws + 106430464);   // Wih0^T [512][64]
    f16*   WoT   = (f16*)(ws + 106496000);   // Wout^T [64][512]
    float* bias0 = (float*)(ws + 106561536);
    float* bias1 = (float*)(ws + 106563584);

    // prep
    k_cast_f16<<<8192, 256, 0, stream>>>(data, D16, 64 * 512 * 64);
    k_pack_whh<<<256, 256, 0, stream>>>(Whh0, Wp0);
    k_pack_whh<<<256, 256, 0, stream>>>(Wih1, WpI);
    k_pack_whh<<<256, 256, 0, stream>>>(Whh1, Wp1);
    k_transpose_f16<<<128, 256, 0, stream>>>(Wih0, WT0, 64, 512);
    k_transpose_f16<<<128, 256, 0, stream>>>(Wout, WoT, 512, 64);
    k_bias_sum<<<2, 256, 0, stream>>>(bih0, bhh0, bias0, bih1, bhh1, bias1);

    // X0 = data @ Wih0 + bias0  (reads D16, must precede flag zeroing)
    dim3 gX(512, 8);
    k_gemm<<<gX, 256, 0, stream>>>(D16, WT0, (void*)X0, bias0, 32768, 512, 64, 0);

    // zero flags (flagA..flagB contiguous = 65536 words) with sc1 stores
    k_zero_flags<<<256, 256, 0, stream>>>(flagA, 2 * BATCH * T_STEPS);

    // fused 3-stage pipelined recurrence: 192 WGs, all co-resident
    k_rnn3<<<dim3(64, 3), 256, 0, stream>>>((const u32*)X0, (u32*)H0, (u32*)X1,
                                            (u32*)X0 /* H1 alias */,
                                            Wp0, WpI, Wp1, bias1, flagA, flagB);

    // OUT = H1 @ Wout + bout -> fp32 d_out
    dim3 gO(512, 1);
    k_gemm<<<gO, 256, 0, stream>>>((const f16*)X0 /* H1 */, WoT, d_out, bout, 32768, 64, 512, 1);
}

// Round 8
// 1475.235 us; speedup vs baseline: 17.9932x; 1.0607x over previous
//
#include <hip/hip_runtime.h>
#include <stdint.h>

// RNN_6725918786207: 2-layer tanh RNN. B=64, T=512, D_IN=64, D_MODEL=512, D_OUT=64.
// Round 10: hide the per-step flag check. r9 post-mortem: removing the barrier's
// vmcnt(0) drain was NEUTRAL (1556 vs 1515/1521) -> store-ack was never the cost.
// Remaining per-step overhead in B/C: the tid0 pre-barrier spin = one sc1 flag
// load from another XCD (~700-900cy) serialized while 255 threads wait. Fix (the
// piece of r7 that was correct and NOT the spill cause): preload the next-needed
// flag pre-dot, pin with empty asm, check post-dot; spin only if 0 (never in
// steady state). fpre dies before the barrier -> zero cross-barrier state, r9's
// 216-VGPR shape preserved. B: step t checks fA[t+2], guarding step t+1's hn
// load (barrier in between). C: step t checks fB[t+1], guarding t+1's xv load.
// Prediction: VGPR 216-220, k_rnn3 1556 -> ~1250-1400us, total ~1290-1440us,
// VALUBusy ~50%. If neutral: overhead is barrier/1-wave latency itself -> next
// lever is an MFMA dot engine in the same pipeline skeleton.

typedef unsigned int u32;
typedef unsigned short u16;
typedef _Float16 f16;
typedef _Float16 h2  __attribute__((ext_vector_type(2)));
typedef _Float16 v8h __attribute__((ext_vector_type(8)));
typedef float    v4f __attribute__((ext_vector_type(4)));

#define T_STEPS 512
#define DM 512
#define BATCH 64

// ---------- small helpers ----------
__device__ __forceinline__ float f16lo(u32 u) {
    u16 s = (u16)(u & 0xffffu); f16 h; __builtin_memcpy(&h, &s, 2); return (float)h;
}
__device__ __forceinline__ float f16hi(u32 u) {
    u16 s = (u16)(u >> 16); f16 h; __builtin_memcpy(&h, &s, 2); return (float)h;
}
__device__ __forceinline__ u32 packh2(float lo, float hi) {
    f16 a = (f16)lo, b = (f16)hi; u16 ua, ub;
    __builtin_memcpy(&ua, &a, 2); __builtin_memcpy(&ub, &b, 2);
    return (u32)ua | ((u32)ub << 16);
}
__device__ __forceinline__ float fdot2u(u32 w, u32 h, float acc) {
    h2 a, b; __builtin_memcpy(&a, &w, 4); __builtin_memcpy(&b, &h, 4);
    return __builtin_amdgcn_fdot2(a, b, acc, false);
}
__device__ __forceinline__ u32 RL(u32 v, int l) {
    return (u32)__builtin_amdgcn_readlane((int)v, l);
}
__device__ __forceinline__ float tanh_fast(float z) {
    float e = __expf(2.0f * z);
    return 1.0f - 2.0f / (e + 1.0f);
}
// agent-scope (device/cross-XCD coherent, sc1) dword access
__device__ __forceinline__ u32 ld_agent(const u32* p) {
    return __hip_atomic_load(p, __ATOMIC_RELAXED, __HIP_MEMORY_SCOPE_AGENT);
}
__device__ __forceinline__ void st_agent(u32* p, u32 v) {
    __hip_atomic_store(p, v, __ATOMIC_RELAXED, __HIP_MEMORY_SCOPE_AGENT);
}

// LDS-only barrier: waits DS ops (hbuf double-buffer ordering) but does NOT drain
// vmcnt -> the per-step sc1 data store keeps flying under the next dot.
#define BARRIER_LG() asm volatile("s_waitcnt lgkmcnt(0)\n\ts_barrier" ::: "memory")

// ---------- prep kernels ----------
__global__ void k_cast_f16(const float* __restrict__ src, f16* __restrict__ dst, int n) {
    int i = blockIdx.x * blockDim.x + threadIdx.x;
    if (i < n) dst[i] = (f16)src[i];
}

// W [512][512] fp32 row-major (k-major) -> Wp [256 pair-rows][256 col-pairs] of uint2:
//   Wp[p][c].x = pack(W[2p][2c],   W[2p+1][2c])
//   Wp[p][c].y = pack(W[2p][2c+1], W[2p+1][2c+1])
__global__ void k_pack_whh(const float* __restrict__ W, uint2* __restrict__ Wp) {
    int i = blockIdx.x * blockDim.x + threadIdx.x;  // 65536
    int p = i >> 8, c = i & 255;
    int k0 = 2 * p, j0 = 2 * c;
    uint2 o;
    o.x = packh2(W[k0 * DM + j0],     W[(k0 + 1) * DM + j0]);
    o.y = packh2(W[k0 * DM + j0 + 1], W[(k0 + 1) * DM + j0 + 1]);
    Wp[p * 256 + c] = o;
}

// src fp32 [R][C] -> dst fp16 [C][R]
__global__ void k_transpose_f16(const float* __restrict__ src, f16* __restrict__ dst, int R, int C) {
    int i = blockIdx.x * blockDim.x + threadIdx.x;
    if (i < R * C) { int r = i / C, c = i % C; dst[c * R + r] = (f16)src[r * C + c]; }
}

__global__ void k_bias_sum(const float* a0, const float* b0, float* o0,
                           const float* a1, const float* b1, float* o1) {
    int i = blockIdx.x * blockDim.x + threadIdx.x;
    if (i < DM) { o0[i] = a0[i] + b0[i]; o1[i] = a1[i] + b1[i]; }
}

// zero the handshake flags with agent-scope stores
__global__ void k_zero_flags(u32* __restrict__ f, int n) {
    int i = blockIdx.x * blockDim.x + threadIdx.x;
    if (i < n) st_agent(&f[i], 0u);
}

// ---------- MFMA f16 GEMM: C[M][N] = A[M][K] @ B[K][N] + bias, B given transposed BT[N][K].
__global__ __launch_bounds__(256) void k_gemm(const f16* __restrict__ A, const f16* __restrict__ BT,
                                              void* __restrict__ Cout, const float* __restrict__ bias,
                                              int M, int N, int K, int out_f32) {
    __shared__ f16 As[64][40];
    __shared__ f16 Bs[64][40];
    int tid = threadIdx.x;
    int mb = blockIdx.x, nb = blockIdx.y;
    int l = tid & 63, w = tid >> 6;
    int q = l >> 4, mr = l & 15;

    int sr = tid >> 2;
    int ko = (tid & 3) * 8;
    const f16* gA = A + (size_t)(mb * 64 + sr) * K + ko;
    const f16* gB = BT + (size_t)(nb * 64 + sr) * K + ko;

    v4f acc[4];
    #pragma unroll
    for (int nt = 0; nt < 4; ++nt) acc[nt] = (v4f){0.f, 0.f, 0.f, 0.f};

    for (int kt = 0; kt < K; kt += 32) {
        *(uint4*)&As[sr][ko] = *(const uint4*)(gA + kt);
        *(uint4*)&Bs[sr][ko] = *(const uint4*)(gB + kt);
        __syncthreads();
        v8h a = *(const v8h*)&As[w * 16 + mr][q * 8];
        #pragma unroll
        for (int nt = 0; nt < 4; ++nt) {
            v8h b = *(const v8h*)&Bs[nt * 16 + mr][q * 8];
            acc[nt] = __builtin_amdgcn_mfma_f32_16x16x32_f16(a, b, acc[nt], 0, 0, 0);
        }
        __syncthreads();
    }

    int row0 = mb * 64 + w * 16 + q * 4;
    #pragma unroll
    for (int nt = 0; nt < 4; ++nt) {
        int col = nb * 64 + nt * 16 + mr;
        float bv = bias[col];
        #pragma unroll
        for (int r = 0; r < 4; ++r) {
            float v = acc[nt][r] + bv;
            if (out_f32) ((float*)Cout)[(size_t)(row0 + r) * N + col] = v;
            else         ((f16*)Cout)[(size_t)(row0 + r) * N + col] = (f16)v;
        }
    }
}

// ---------- fused 3-stage pipelined recurrence ----------
// grid (64, 3): blockIdx.x = batch, blockIdx.y = role.
//   role 0 (A): h0[t] = tanh(X0[t] + h0[t-1] @ Whh0)  -> H0 (sc1)
//   role 1 (B): x1[t] = h0[t] @ Wih1 + bias1          -> X1 (sc1)
//   role 2 (C): h1[t] = tanh(x1[t] + h1[t-1] @ Whh1)  -> H1 (plain)
// Per step: BARRIER_LG (LDS wait only) -> flag publish (proof via natural vmem
// waits, r9) -> data loads -> hidden flag PRELOAD for the step after -> dot ->
// store fire-and-forget -> post-dot flag check (spin only if 0; never in steady
// state). No state lives across a barrier. All 192 WGs co-resident (1 WG/CU by
// LDS) -> spins deadlock-free; bounded-spin guard fails fast, not a hang.

#define COMPUTE_DOT() do {                                                        \
    _Pragma("unroll")                                                             \
    for (int p = 0; p < 192; p += 2) {                                            \
        u32 hA = RL(hr[p >> 6], p & 63);                                          \
        u32 hB = RL(hr[(p + 1) >> 6], (p + 1) & 63);                              \
        u32 y0, y1;                                                               \
        asm volatile("v_accvgpr_read_b32 %0, %1" : "=v"(y0) : "a"(w1a[p]));       \
        asm volatile("v_accvgpr_read_b32 %0, %1" : "=v"(y1) : "a"(w1a[p + 1]));   \
        a0 = fdot2u(w0[p], hA, a0);                                               \
        a1 = fdot2u(y0, hA, a1);                                                  \
        a2 = fdot2u(w0[p + 1], hB, a2);                                           \
        a3 = fdot2u(y1, hB, a3);                                                  \
    }                                                                             \
    _Pragma("unroll")                                                             \
    for (int q2 = 0; q2 < 32; ++q2) {                                             \
        uint4 wv = ldsW[q2 * 256 + tid];                                          \
        int p0 = 192 + 2 * q2;                                                    \
        u32 hA = RL(hr[3], p0 & 63);                                              \
        u32 hB = RL(hr[3], (p0 + 1) & 63);                                        \
        a0 = fdot2u(wv.x, hA, a0);                                                \
        a1 = fdot2u(wv.y, hA, a1);                                                \
        a2 = fdot2u(wv.z, hB, a2);                                                \
        a3 = fdot2u(wv.w, hB, a3);                                                \
    }                                                                             \
} while (0)

// tid0-only spin. Bounded: guard turns a coherence surprise into a fast wrong
// answer instead of a harness hang.
#define SPIN(ptr) do { int g_ = 0;                                                \
    while (!dead && __hip_atomic_load((ptr), __ATOMIC_RELAXED,                    \
                                      __HIP_MEMORY_SCOPE_AGENT) == 0u) {          \
        __builtin_amdgcn_s_sleep(2);                                              \
        if (++g_ > (1 << 21)) dead = 1;                                           \
    } } while (0)

__global__ __launch_bounds__(256, 1) void k_rnn3(const u32* __restrict__ X0,
                                                 u32* __restrict__ H0,
                                                 u32* __restrict__ X1,
                                                 u32* __restrict__ H1,
                                                 const uint2* __restrict__ Wp0,
                                                 const uint2* __restrict__ WpI,
                                                 const uint2* __restrict__ Wp1,
                                                 const float* __restrict__ bias1,
                                                 u32* __restrict__ flagA,
                                                 u32* __restrict__ flagB) {
    __shared__ uint4 ldsW[32 * 256];   // 128 KiB: pair-rows 192..255
    __shared__ u32 hbuf[2][256];       // double-buffered recurrent h (roles A, C)

    int b = blockIdx.x, role = blockIdx.y;
    int tid = threadIdx.x, lane = tid & 63;

    const uint2* Wp = (role == 0) ? Wp0 : (role == 1) ? WpI : Wp1;

    // stage LDS-resident part of W
    for (int i = tid; i < 32 * 256; i += 256) {
        int q2 = i >> 8, c = i & 255;
        uint2 lo = Wp[(192 + 2 * q2) * 256 + c];
        uint2 hi = Wp[(193 + 2 * q2) * 256 + c];
        ldsW[i] = make_uint4(lo.x, lo.y, hi.x, hi.y);
    }

    // register-resident part: 192 ArchVGPRs (w0) + 192 AGPRs (w1a)
    u32 w0[192];
    u32 w1a[192];
    #pragma unroll
    for (int p = 0; p < 192; ++p) {
        uint2 t2 = Wp[p * 256 + tid];
        asm volatile("v_mov_b32 %0, %1" : "=v"(w0[p]) : "v"(t2.x));
        asm volatile("v_accvgpr_write_b32 %0, %1" : "=a"(w1a[p]) : "v"(t2.y));
    }

    hbuf[0][tid] = 0u;
    __syncthreads();

    if (role == 0) {
        // ---- A: layer-0 recurrence; store flies under step t+1's dot ----
        const u32* Xb = X0 + (size_t)b * T_STEPS * 256;
        u32* Hb = H0 + (size_t)b * T_STEPS * 256;
        u32* fA = flagA + b * T_STEPS;
        int cur = 0;
        for (int t = 0; t < T_STEPS; ++t) {
            BARRIER_LG();                           // LDS wait only; no vmem drain
            if (tid == 0 && t >= 2) st_agent(&fA[t - 2], 1u);  // proven by xv(t-1) use
            u32 hr[4];
            #pragma unroll
            for (int r = 0; r < 4; ++r) hr[r] = hbuf[cur][r * 64 + lane];
            u32 xv = Xb[t * 256 + tid];             // consumed at end: proves store(t-1)

            float a0 = 0.f, a1 = 0.f, a2 = 0.f, a3 = 0.f;
            COMPUTE_DOT();

            float z0 = a0 + f16lo(xv) + a2;
            float z1 = a1 + f16hi(xv) + a3;
            u32 hp = packh2(tanh_fast(z0), tanh_fast(z1));
            hbuf[cur ^ 1][tid] = hp;
            st_agent(&Hb[t * 256 + tid], hp);       // fire-and-forget
            cur ^= 1;
        }
        __syncthreads();                            // full drain: stores T-2, T-1 proven
        if (tid == 0) { st_agent(&fA[T_STEPS - 2], 1u); st_agent(&fA[T_STEPS - 1], 1u); }
    } else if (role == 1) {
        // ---- B: x1[t] = h0[t] @ Wih1 + bias1; flag check hidden under the dot ----
        const u32* Hb = H0 + (size_t)b * T_STEPS * 256;
        u32* Xb1 = X1 + (size_t)b * T_STEPS * 256;
        u32* fA = flagA + b * T_STEPS;
        u32* fB = flagB + b * T_STEPS;
        float bl = bias1[2 * tid], bh = bias1[2 * tid + 1];
        int dead = 0;

        if (tid == 0) { SPIN(&fA[0]); SPIN(&fA[1]); }   // bootstrap: h0[0], h0[1]
        BARRIER_LG();
        u32 hr[4];
        #pragma unroll
        for (int r = 0; r < 4; ++r) hr[r] = ld_agent(&Hb[r * 64 + lane]);

        for (int t = 0; t < T_STEPS; ++t) {
            BARRIER_LG();
            if (tid == 0 && t >= 2) st_agent(&fB[t - 2], 1u);   // proven by tail vmcnt(1)
            u32 hn[4] = {0u, 0u, 0u, 0u};
            if (t + 1 < T_STEPS) {                  // fA[t+1] confirmed at end of step t-1
                #pragma unroll
                for (int r = 0; r < 4; ++r)
                    hn[r] = ld_agent(&Hb[(size_t)(t + 1) * 256 + r * 64 + lane]);
            }
            u32 fpre = 1u;                          // hidden preload of fA[t+2]
            if (tid == 0 && t + 2 < T_STEPS) {
                fpre = ld_agent(&fA[t + 2]);
                asm volatile("" :: "v"(fpre));      // pin issue point pre-dot
            }

            float a0 = 0.f, a1 = 0.f, a2 = 0.f, a3 = 0.f;
            COMPUTE_DOT();

            u32 xp = packh2(a0 + a2 + bl, a1 + a3 + bh);
            st_agent(&Xb1[t * 256 + tid], xp);      // fire-and-forget
            // leave only the just-issued store outstanding: forces hn(t) returned
            // and (in-order retire) store(t-1) complete — both old, ~0 cost
            asm volatile("s_waitcnt vmcnt(1)" ::: "memory");
            if (tid == 0 && t + 2 < T_STEPS && fpre == 0u) SPIN(&fA[t + 2]);
            #pragma unroll
            for (int r = 0; r < 4; ++r) hr[r] = hn[r];
        }
        __syncthreads();                            // full drain: stores T-2, T-1 proven
        if (tid == 0) { st_agent(&fB[T_STEPS - 2], 1u); st_agent(&fB[T_STEPS - 1], 1u); }
    } else {
        // ---- C: layer-1 recurrence; flag check + xv load hidden under the dot ----
        const u32* Xb1 = X1 + (size_t)b * T_STEPS * 256;
        u32* Hb1 = H1 + (size_t)b * T_STEPS * 256;
        u32* fB = flagB + b * T_STEPS;
        int dead = 0;
        int cur = 0;
        if (tid == 0) SPIN(&fB[0]);                 // bootstrap: x1[0] ready
        for (int t = 0; t < T_STEPS; ++t) {
            BARRIER_LG();
            u32 xv = ld_agent(&Xb1[t * 256 + tid]); // guarded by check at end of t-1
            u32 fpre = 1u;                          // hidden preload of fB[t+1]
            if (tid == 0 && t + 1 < T_STEPS) {
                fpre = ld_agent(&fB[t + 1]);
                asm volatile("" :: "v"(fpre));      // pin issue point pre-dot
            }

            u32 hr[4];
            #pragma unroll
            for (int r = 0; r < 4; ++r) hr[r] = hbuf[cur][r * 64 + lane];

            float a0 = 0.f, a1 = 0.f, a2 = 0.f, a3 = 0.f;
            COMPUTE_DOT();

            float z0 = a0 + f16lo(xv) + a2;
            float z1 = a1 + f16hi(xv) + a3;
            u32 hp = packh2(tanh_fast(z0), tanh_fast(z1));
            hbuf[cur ^ 1][tid] = hp;
            Hb1[t * 256 + tid] = hp;                // plain fire-and-forget
            if (tid == 0 && t + 1 < T_STEPS && fpre == 0u) SPIN(&fB[t + 1]);
            cur ^= 1;
        }
        // final H1 store drained by kernel-end implicit release
    }
}

// ---------- launch ----------
extern "C" void kernel_launch(void* const* d_in, const int* in_sizes, int n_in,
                              void* d_out, int out_size, void* d_ws, size_t ws_size,
                              hipStream_t stream) {
    (void)in_sizes; (void)n_in; (void)out_size; (void)ws_size;
    const float* data = (const float*)d_in[0];
    const float* Wih0 = (const float*)d_in[1];
    const float* bih0 = (const float*)d_in[2];
    const float* Whh0 = (const float*)d_in[3];
    const float* bhh0 = (const float*)d_in[4];
    const float* Wih1 = (const float*)d_in[5];
    const float* bih1 = (const float*)d_in[6];
    const float* Whh1 = (const float*)d_in[7];
    const float* bhh1 = (const float*)d_in[8];
    const float* Wout = (const float*)d_in[9];
    const float* bout = (const float*)d_in[10];

    char* ws = (char*)d_ws;
    // workspace layout (bytes); total = 106,565,632
    f16*   X0    = (f16*)(ws + 0);           // [32768][512] f16; H1 aliased here:
                                             // C writes H1[b][t] only after fB[t] <-
                                             // A far past step t, so A read X0[b][t]
                                             // long before.
    f16*   H0    = (f16*)(ws + 33554432);    // [32768][512] f16 (A -> B, sc1)
    f16*   X1    = (f16*)(ws + 67108864);    // [32768][512] f16 (B -> C, sc1)
    f16*   D16   = (f16*)(ws + 100663296);   // data fp16 [32768][64] (dead after X0 GEMM)
    u32*   flagA = (u32*)(ws + 100663296);   // 128 KiB, aliases D16 head (zeroed post-GEMM)
    u32*   flagB = (u32*)(ws + 100794368);   // 128 KiB
    uint2* Wp0   = (uint2*)(ws + 104857600); // packed Whh0
    uint2* WpI   = (uint2*)(ws + 105381888); // packed Wih1
    uint2* Wp1   = (uint2*)(ws + 105906176); // packed Whh1
    f16*   WT0   = (f16*)(ws + 106430464);   // Wih0^T [512][64]
    f16*   WoT   = (f16*)(ws + 106496000);   // Wout^T [64][512]
    float* bias0 = (float*)(ws + 106561536);
    float* bias1 = (float*)(ws + 106563584);

    // prep
    k_cast_f16<<<8192, 256, 0, stream>>>(data, D16, 64 * 512 * 64);
    k_pack_whh<<<256, 256, 0, stream>>>(Whh0, Wp0);
    k_pack_whh<<<256, 256, 0, stream>>>(Wih1, WpI);
    k_pack_whh<<<256, 256, 0, stream>>>(Whh1, Wp1);
    k_transpose_f16<<<128, 256, 0, stream>>>(Wih0, WT0, 64, 512);
    k_transpose_f16<<<128, 256, 0, stream>>>(Wout, WoT, 512, 64);
    k_bias_sum<<<2, 256, 0, stream>>>(bih0, bhh0, bias0, bih1, bhh1, bias1);

    // X0 = data @ Wih0 + bias0  (reads D16, must precede flag zeroing)
    dim3 gX(512, 8);
    k_gemm<<<gX, 256, 0, stream>>>(D16, WT0, (void*)X0, bias0, 32768, 512, 64, 0);

    // zero flags (flagA..flagB contiguous = 65536 words) with sc1 stores
    k_zero_flags<<<256, 256, 0, stream>>>(flagA, 2 * BATCH * T_STEPS);

    // fused 3-stage pipelined recurrence: 192 WGs, all co-resident
    k_rnn3<<<dim3(64, 3), 256, 0, stream>>>((const u32*)X0, (u32*)H0, (u32*)X1,
                                            (u32*)X0 /* H1 alias */,
                                            Wp0, WpI, Wp1, bias1, flagA, flagB);

    // OUT = H1 @ Wout + bout -> fp32 d_out
    dim3 gO(512, 1);
    k_gemm<<<gO, 256, 0, stream>>>((const f16*)X0 /* H1 */, WoT, d_out, bout, 32768, 64, 512, 1);
}